// Round 10
// baseline (533.829 us; speedup 1.0000x reference)
//
#include <hip/hip_runtime.h>
#include <math.h>

// Problem constants
#define BZ 2
#define HH 56
#define WW 56
#define LL 3136      // 56*56
#define CC 96        // DIM
#define DI 192       // DINNER
#define NS 16        // DSTATE
#define RR 6         // DTRANK
#define NT 49        // LL/64
#define NCH 98       // scan chunks (32 positions each)
#define CH 32        // chunk length

// Workspace layout (floats)
#define OFF_CONV   0
#define OFF_XMRAW  602112
#define OFF_Z      1806336
#define OFF_V1     3010560
#define OFF_V2     4214784
#define OFF_DT     5419008
#define OFF_BS     10235904
#define OFF_CS     10637312
#define OFF_Y      11038720
#define OFF_Y13    15855616
#define OFF_T      18264064
#define OFF_W2     19468288
// total 19486720 floats = ~78 MB

__device__ __forceinline__ float softplusf(float x) {
    if (x > 20.f) return x;
    return log1pf(__expf(x));
}

// ---------------- K0: W2[o][d] = sum_j fus_w[o][96+j] * out_proj_w[j][d] ----------------
__global__ __launch_bounds__(64) void k0_w2(const float* __restrict__ fus_w,
                                            const float* __restrict__ opw,
                                            float* __restrict__ W2) {
    int i = blockIdx.x * 64 + threadIdx.x;
    if (i >= CC * DI) return;
    int o = i / DI, d = i % DI;
    float acc = 0.f;
    for (int j = 0; j < CC; ++j)
        acc += fus_w[o * DI + CC + j] * opw[j * DI + d];
    W2[i] = acc;
}

// ---------------- K0c: negA[k][d][n] = -exp(A_logs) ----------------
__global__ __launch_bounds__(256) void k0c_negA(const float* __restrict__ A_logs,
                                                float* __restrict__ negA) {
    int i = blockIdx.x * 256 + threadIdx.x;
    if (i < 4 * DI * NS) negA[i] = -__expf(A_logs[i]);
}

// ---------------- K1a: dwconv3 + bn1 + relu (elementwise, fully parallel) ----------------
__global__ __launch_bounds__(256) void k1a_dw(const float* __restrict__ x,
    const float* __restrict__ dw_w, const float* __restrict__ dw_b,
    const float* __restrict__ bn1_g, const float* __restrict__ bn1_b,
    const float* __restrict__ bn1_m, const float* __restrict__ bn1_v,
    float* __restrict__ cbuf) {
    int i = blockIdx.x * 256 + threadIdx.x;
    if (i >= BZ * LL * CC) return;
    int c = i % CC;
    int bl = i / CC;
    int l = bl % LL, b = bl / LL;
    int h = l / WW, w = l % WW;
    float acc = dw_b[c];
    #pragma unroll
    for (int dy = -1; dy <= 1; ++dy) {
        int hh = h + dy; if (hh < 0 || hh >= HH) continue;
        #pragma unroll
        for (int dx = -1; dx <= 1; ++dx) {
            int ww = w + dx; if (ww < 0 || ww >= WW) continue;
            acc += x[((b * HH + hh) * WW + ww) * CC + c] * dw_w[c * 9 + (dy + 1) * 3 + (dx + 1)];
        }
    }
    float inv = rsqrtf(bn1_v[c] + 1e-5f);
    float v = (acc - bn1_m[c]) * inv * bn1_g[c] + bn1_b[c];
    cbuf[i] = fmaxf(v, 0.f);
}

// ---------------- K1b: 1x1 conv (pw) + bn2 -> conv_out (B,L,96) NHWC ----------------
__global__ __launch_bounds__(256) void k1b_pw(const float* __restrict__ cbuf,
    const float* __restrict__ pw_w, const float* __restrict__ pw_b,
    const float* __restrict__ bn2_g, const float* __restrict__ bn2_b,
    const float* __restrict__ bn2_m, const float* __restrict__ bn2_v,
    float* __restrict__ conv_out) {
    int t0 = blockIdx.x * 64;
    int og = blockIdx.y;
    int b = blockIdx.z;
    int lane = threadIdx.x & 63;
    int wvu = __builtin_amdgcn_readfirstlane(threadIdx.x >> 6);
    __shared__ float ct[CC * 65];      // [c][p]
    __shared__ float res[64 * 49];     // [p][48 outs + pad]
    const float* cb = cbuf + (b * LL + t0) * CC;
    for (int e = threadIdx.x; e < 64 * CC; e += 256) {
        int p = e / CC, c = e % CC;
        ct[c * 65 + p] = cb[e];
    }
    __syncthreads();
    int o0 = og * 48 + wvu * 12;
    float acc[12];
    const float* pb = pw_b + o0;
    #pragma unroll
    for (int j = 0; j < 12; ++j) acc[j] = pb[j];
    const float* wb = pw_w + o0 * CC;              // uniform -> s_load
    for (int c = 0; c < CC; ++c) {
        float xv = ct[c * 65 + lane];
        #pragma unroll
        for (int j = 0; j < 12; ++j)
            acc[j] += xv * wb[j * CC + c];
    }
    #pragma unroll
    for (int j = 0; j < 12; ++j) {
        int o = o0 + j;
        float inv = rsqrtf(bn2_v[o] + 1e-5f);
        res[lane * 49 + wvu * 12 + j] = (acc[j] - bn2_m[o]) * inv * bn2_g[o] + bn2_b[o];
    }
    __syncthreads();
    float* ob = conv_out + (b * LL + t0) * CC + og * 48;
    for (int e = threadIdx.x; e < 64 * 48; e += 256) {
        int pl = e / 48, o = e % 48;
        ob[pl * CC + o] = res[pl * 49 + o];
    }
}

// ---------------- K2: LN + in_proj -> xm_raw (B,192,L), z (B,192,L) ----------------
__global__ __launch_bounds__(256) void k2_inproj(const float* __restrict__ x,
    const float* __restrict__ ln_g, const float* __restrict__ ln_b,
    const float* __restrict__ ipw,
    float* __restrict__ xm_raw, float* __restrict__ z_buf) {
    int t0 = blockIdx.x * 64;
    int og = blockIdx.y;       // 0..7, 48 outputs each
    int b = blockIdx.z;
    int lane = threadIdx.x & 63;
    int wv = threadIdx.x >> 6;
    int wvu = __builtin_amdgcn_readfirstlane(wv);
    __shared__ float xt[64 * 97];      // [p][c]
    __shared__ float xn[96 * 65];      // [c][p] normalized
    __shared__ float ps[4][64], ps2[4][64];
    const float* xb = x + (b * LL + t0) * CC;
    for (int e = threadIdx.x; e < 64 * CC; e += 256) {
        int p = e / CC, c = e % CC;
        xt[p * 97 + c] = xb[e];
    }
    __syncthreads();
    float s = 0.f, s2 = 0.f;
    #pragma unroll
    for (int j = 0; j < 24; ++j) {
        float v = xt[lane * 97 + wvu * 24 + j];
        s += v; s2 += v * v;
    }
    ps[wv][lane] = s; ps2[wv][lane] = s2;
    __syncthreads();
    float st = 0.f, st2 = 0.f;
    #pragma unroll
    for (int i = 0; i < 4; ++i) { st += ps[i][lane]; st2 += ps2[i][lane]; }
    float m = st * (1.f / 96.f);
    float inv = rsqrtf(st2 * (1.f / 96.f) - m * m + 1e-5f);
    #pragma unroll
    for (int j = 0; j < 24; ++j) {
        int c = wvu * 24 + j;
        xn[c * 65 + lane] = (xt[lane * 97 + c] - m) * inv * ln_g[c] + ln_b[c];
    }
    __syncthreads();
    float acc[12];
    #pragma unroll
    for (int j = 0; j < 12; ++j) acc[j] = 0.f;
    int o0 = og * 48 + wvu * 12;
    const float* wbase = ipw + o0 * CC;       // uniform -> s_load
    for (int c = 0; c < CC; ++c) {
        float xv = xn[c * 65 + lane];
        #pragma unroll
        for (int j = 0; j < 12; ++j)
            acc[j] += xv * wbase[j * CC + c];
    }
    int p = t0 + lane;
    #pragma unroll
    for (int j = 0; j < 12; ++j) {
        int out = o0 + j;
        if (out < DI) xm_raw[(b * DI + out) * LL + p] = acc[j];
        else          z_buf[(b * DI + (out - DI)) * LL + p] = acc[j];
    }
}

// ---------------- K3: dwconv3 + SiLU -> v1 (row-major), v2 (col-major) ----------------
__global__ __launch_bounds__(256) void k3_dw(const float* __restrict__ xm_raw,
    const float* __restrict__ conv_w, const float* __restrict__ conv_b,
    float* __restrict__ v1, float* __restrict__ v2) {
    int bd = blockIdx.x;
    int half = blockIdx.y;
    int d = bd % DI;
    int h0 = half * 28;
    __shared__ float tile[28 * 57];
    const float* src = xm_raw + bd * LL;
    float wloc[9];
    #pragma unroll
    for (int i = 0; i < 9; ++i) wloc[i] = conv_w[d * 9 + i];
    float bias = conv_b[d];
    for (int e = threadIdx.x; e < 28 * WW; e += 256) {
        int hl = e / WW, w = e % WW;
        int h = h0 + hl;
        float acc = bias;
        #pragma unroll
        for (int dy = -1; dy <= 1; ++dy) {
            int hh = h + dy; if (hh < 0 || hh >= HH) continue;
            #pragma unroll
            for (int dx = -1; dx <= 1; ++dx) {
                int ww = w + dx; if (ww < 0 || ww >= WW) continue;
                acc += src[hh * WW + ww] * wloc[(dy + 1) * 3 + (dx + 1)];
            }
        }
        float sig = 1.f / (1.f + __expf(-acc));
        float v = acc * sig;
        v1[bd * LL + h * WW + w] = v;
        tile[hl * 57 + w] = v;
    }
    __syncthreads();
    for (int e = threadIdx.x; e < 28 * WW; e += 256) {
        int w = e / 28, hl = e % 28;
        v2[bd * LL + w * HH + h0 + hl] = tile[hl * 57 + w];
    }
}

// ---------------- K4a: x_proj — 4-wave blocks, no LDS, 10 rows/wave ----------------
// grid (NT, 4, BZ) x 256. Each wave reads the same coalesced v stream (L1-shared);
// weights wave-uniform s_loads. Rows: 0-9,10-19,20-29,28-37 (overlap benign).
__global__ __launch_bounds__(256) void k4a_xproj(const float* __restrict__ v1,
    const float* __restrict__ v2, const float* __restrict__ xpw,
    float* __restrict__ dtr_g, float* __restrict__ B_s, float* __restrict__ C_s) {
    int tile = blockIdx.x;
    int k = blockIdx.y, b = blockIdx.z;
    int lane = threadIdx.x & 63;
    int wvu = __builtin_amdgcn_readfirstlane(threadIdx.x >> 6);
    int t0 = tile * 64;
    int r0 = wvu * 10; if (r0 > 28) r0 = 28;
    const float* src = ((k & 1) == 0 ? v1 : v2) + b * DI * LL + t0;
    float acc[10];
    #pragma unroll
    for (int i = 0; i < 10; ++i) acc[i] = 0.f;
    const float* wbase = xpw + (k * 38 + r0) * DI;   // uniform -> s_load
    for (int d = 0; d < DI; ++d) {
        float xv = src[d * LL + lane];
        #pragma unroll
        for (int i = 0; i < 10; ++i)
            acc[i] += xv * wbase[i * DI + d];
    }
    int bk = b * 4 + k;
    int p = t0 + lane;
    #pragma unroll
    for (int i = 0; i < 10; ++i) {
        int c = r0 + i;
        if (c < RR) {
            dtr_g[(bk * RR + c) * LL + p] = acc[i];
        } else if (c < RR + NS) {
            B_s[(bk * NS + (c - RR)) * LL + p] = acc[i];
        } else {
            C_s[(bk * NS + (c - RR - NS)) * LL + p] = acc[i];
        }
    }
}

// ---------------- K4b: dt_proj + softplus (streaming write) ----------------
__global__ __launch_bounds__(256) void k4b_dt(const float* __restrict__ dtr_g,
    const float* __restrict__ dtw, const float* __restrict__ dtb,
    float* __restrict__ dt_s) {
    int t0 = blockIdx.x * 64;
    int k = blockIdx.y, b = blockIdx.z;
    int lane = threadIdx.x & 63;
    int wvu = __builtin_amdgcn_readfirstlane(threadIdx.x >> 6);
    int bk = b * 4 + k;
    int p = t0 + lane;
    float r[RR];
    #pragma unroll
    for (int i = 0; i < RR; ++i) r[i] = dtr_g[(bk * RR + i) * LL + p];
    for (int i = 0; i < 48; ++i) {
        int d = wvu * 48 + i;
        float a = dtb[k * DI + d];
        const float* wr = dtw + (k * DI + d) * RR;   // uniform -> s_load
        #pragma unroll
        for (int q = 0; q < RR; ++q)
            a += r[q] * wr[q];
        dt_s[(bk * DI + d) * LL + p] = softplusf(a);
    }
}

// ---------------- K5a: scan phase 1 — register dt/u/y, forward-only code ----------
// Backward scans handled by reversed (static) load/store permutation, so only ONE
// unrolled 32-step body exists (~16 KB — fits I$). LDS = bc only (4.6 KB).
__global__ __launch_bounds__(64, 4) void k5a_scan(const float* __restrict__ dt_s,
    const float* __restrict__ B_s, const float* __restrict__ C_s,
    const float* __restrict__ v1, const float* __restrict__ v2,
    const float* __restrict__ A_logs, float* __restrict__ y_scan,
    float* __restrict__ hl_buf, float* __restrict__ Tbuf) {
    int bx = blockIdx.x;
    int dg = bx % 3, c = bx / 3;
    int k = blockIdx.y;
    int b = blockIdx.z;
    int bk = b * 4 + k;
    int lane = threadIdx.x;
    int d = dg * 64 + lane;
    bool fwd = (k < 2);
    int s0 = fwd ? c * CH : (LL - (c + 1) * CH);
    __shared__ float bc[CH * 36];        // [scan-pos][36]: B 0..15, C 16..31, pad
    float Ae[16];
    const float* ap = A_logs + (k * DI + d) * NS;
    #pragma unroll
    for (int n = 0; n < 16; ++n) Ae[n] = -__expf(ap[n]) * 1.442695040888963f;
    const float4* dtp4 = (const float4*)(dt_s + (bk * DI + d) * LL + s0);
    const float4* up4  = (const float4*)((((k & 1) == 0) ? v1 : v2) + (b * DI + d) * LL + s0);
    float4 dt4[8], u4[8];
    if (fwd) {
        #pragma unroll
        for (int i = 0; i < 8; ++i) { dt4[i] = dtp4[i]; u4[i] = up4[i]; }
    } else {
        #pragma unroll
        for (int i = 0; i < 8; ++i) {
            float4 a = dtp4[7 - i], q = up4[7 - i];
            dt4[i] = make_float4(a.w, a.z, a.y, a.x);
            u4[i]  = make_float4(q.w, q.z, q.y, q.x);
        }
    }
    float* dts = (float*)dt4;
    float* us  = (float*)u4;             // y overwrites consumed u slots
    int pr = lane >> 5, pc = lane & 31;
    int si = fwd ? pc : (31 - pc);       // scan-order slot for source column pc
    #pragma unroll
    for (int i = 0; i < 8; ++i) {
        int nn = i * 2 + pr;
        bc[si * 36 + nn]      = B_s[(bk * NS + nn) * LL + s0 + pc];
        bc[si * 36 + 16 + nn] = C_s[(bk * NS + nn) * LL + s0 + pc];
    }
    __syncthreads();
    float h[16];
    #pragma unroll
    for (int n = 0; n < 16; ++n) h[n] = 0.f;
    float cum = 0.f;
    #pragma unroll
    for (int j = 0; j < CH; ++j) {
        float dtv = dts[j];
        float uv  = us[j];
        float du = dtv * uv;
        cum += dtv;
        const float4* row4 = (const float4*)&bc[j * 36];
        float4 b0 = row4[0], b1 = row4[1], b2 = row4[2], b3 = row4[3];
        float4 c0 = row4[4], c1 = row4[5], c2 = row4[6], c3 = row4[7];
        float bv[16] = {b0.x,b0.y,b0.z,b0.w, b1.x,b1.y,b1.z,b1.w,
                        b2.x,b2.y,b2.z,b2.w, b3.x,b3.y,b3.z,b3.w};
        float cv[16] = {c0.x,c0.y,c0.z,c0.w, c1.x,c1.y,c1.z,c1.w,
                        c2.x,c2.y,c2.z,c2.w, c3.x,c3.y,c3.z,c3.w};
        float y = 0.f;
        #pragma unroll
        for (int n = 0; n < 16; ++n) {
            h[n] = exp2f(dtv * Ae[n]) * h[n] + du * bv[n];
            y += h[n] * cv[n];
        }
        us[j] = y;
    }
    float4* yp4 = (float4*)(y_scan + (bk * DI + d) * LL + s0);
    if (fwd) {
        #pragma unroll
        for (int i = 0; i < 8; ++i) yp4[i] = u4[i];
    } else {
        #pragma unroll
        for (int i = 0; i < 8; ++i) {
            float4 a = u4[7 - i];
            yp4[i] = make_float4(a.w, a.z, a.y, a.x);
        }
    }
    float4* hp4 = (float4*)(hl_buf + (bk * NCH + c) * (DI * NS) + d * NS);
    hp4[0] = make_float4(h[0], h[1], h[2], h[3]);
    hp4[1] = make_float4(h[4], h[5], h[6], h[7]);
    hp4[2] = make_float4(h[8], h[9], h[10], h[11]);
    hp4[3] = make_float4(h[12], h[13], h[14], h[15]);
    Tbuf[(bk * NCH + c) * DI + d] = cum;
}

// ---------------- K5c: scan phase 2 — serial chunk combine, in place, prefetched --------
__global__ __launch_bounds__(64) void k5c_comb(float* __restrict__ hl_buf,
    const float* __restrict__ Tbuf, const float* __restrict__ negA) {
    int dg = blockIdx.x, k = blockIdx.y, b = blockIdx.z;
    int lane = threadIdx.x, dl = lane >> 4, n = lane & 15;
    int d = dg * 4 + dl;
    int bk = b * 4 + k;
    float Av = negA[(k * DI + d) * NS + n];
    float H = 0.f;
    float* slot0 = hl_buf + (bk * NCH + 0) * (DI * NS) + dg * 64 + lane;
    float hl_next = *slot0;
    float T_next = Tbuf[(bk * NCH + 0) * DI + d];
    for (int c = 0; c < NCH; ++c) {
        float hl = hl_next, T = T_next;
        if (c + 1 < NCH) {
            hl_next = hl_buf[(bk * NCH + c + 1) * (DI * NS) + dg * 64 + lane];
            T_next  = Tbuf[(bk * NCH + c + 1) * DI + d];
        }
        hl_buf[(bk * NCH + c) * (DI * NS) + dg * 64 + lane] = H;
        H = hl + __expf(Av * T) * H;
    }
}

// ---------------- K5d: scan phase 3 — parallel correction (prefix via shfl) ----------
__global__ __launch_bounds__(256) void k5d_corr(const float* __restrict__ dt_s,
    const float* __restrict__ C_s, const float* __restrict__ hin,
    const float* __restrict__ negA, float* __restrict__ y_scan) {
    int t = blockIdx.x;
    int k = blockIdx.y, b = blockIdx.z;
    bool fwd = (k < 2);
    int c  = fwd ? (t + 1) : (NCH - 1 - t);
    int s0 = fwd ? (t + 1) * CH : t * CH;
    int p32 = threadIdx.x & 31, sl = threadIdx.x >> 5;
    int bk = b * 4 + k;
    __shared__ float c_l[16 * 33];
    for (int e = threadIdx.x; e < 16 * CH; e += 256) {
        int n = e >> 5, s = e & 31;
        c_l[n * 33 + s] = C_s[(bk * NS + n) * LL + s0 + s];
    }
    __syncthreads();
    for (int j = 0; j < 24; ++j) {
        int d = sl * 24 + j;
        float dtv = dt_s[(bk * DI + d) * LL + s0 + p32];
        float cum = dtv;
        if (fwd) {
            #pragma unroll
            for (int off = 1; off < 32; off <<= 1) {
                float o = __shfl_up(cum, off, 32);
                if (p32 >= off) cum += o;
            }
        } else {
            #pragma unroll
            for (int off = 1; off < 32; off <<= 1) {
                float o = __shfl_down(cum, off, 32);
                if (p32 < 32 - off) cum += o;
            }
        }
        const float* hp = hin + (bk * NCH + c) * (DI * NS) + d * 16;
        const float* ap = negA + (k * DI + d) * NS;
        float acc = 0.f;
        #pragma unroll
        for (int n = 0; n < 16; ++n) {
            acc += c_l[n * 33 + p32] * __expf(ap[n] * cum) * hp[n];
        }
        y_scan[(bk * DI + d) * LL + s0 + p32] += acc;
    }
}

// ---------------- K5b: transpose y for k=1,3 ----------------
__global__ __launch_bounds__(256) void k5b_tr(const float* __restrict__ y_scan,
                                              float* __restrict__ y13t) {
    int idx = blockIdx.x;
    int d = idx % DI;
    int bk = idx / DI;
    int kk = bk % 2, b = bk / 2;
    int k = (kk == 0) ? 1 : 3;
    __shared__ float tile[HH * 57];
    const float* src = y_scan + ((b * 4 + k) * DI + d) * LL;
    for (int e = threadIdx.x; e < LL; e += 256) {
        int w = e / HH, h = e % HH;
        tile[h * 57 + w] = src[e];
    }
    __syncthreads();
    float* dst = y13t + idx * LL;
    for (int e = threadIdx.x; e < LL; e += 256) {
        int h = e / WW, w = e % WW;
        dst[e] = tile[h * 57 + w];
    }
}

// ---------------- K6: gather 4 dirs + D*u + out_norm + silu(z) gate -> t ----------------
__global__ __launch_bounds__(256) void k6_gather(const float* __restrict__ y_scan,
    const float* __restrict__ y13t, const float* __restrict__ v1,
    const float* __restrict__ z_buf, const float* __restrict__ Ds,
    const float* __restrict__ ong, const float* __restrict__ onb,
    float* __restrict__ t_buf) {
    int t0 = blockIdx.x * 16;
    int b = blockIdx.y;
    int p16 = threadIdx.x & 15, sl = threadIdx.x >> 4;
    int p = t0 + p16;
    __shared__ float yv[DI * 17];
    __shared__ float ps[16][16], ps2[16][16];
    float s = 0.f, s2 = 0.f;
    for (int j = 0; j < 12; ++j) {
        int d = sl * 12 + j;
        float dsum = Ds[d] + Ds[DI + d] + Ds[2 * DI + d] + Ds[3 * DI + d];
        float val = y_scan[((b * 4 + 0) * DI + d) * LL + p]
                  + y_scan[((b * 4 + 2) * DI + d) * LL + p]
                  + y13t[((b * 2 + 0) * DI + d) * LL + p]
                  + y13t[((b * 2 + 1) * DI + d) * LL + p]
                  + v1[(b * DI + d) * LL + p] * dsum;
        yv[d * 17 + p16] = val;
        s += val; s2 += val * val;
    }
    ps[sl][p16] = s; ps2[sl][p16] = s2;
    __syncthreads();
    float st = 0.f, st2 = 0.f;
    #pragma unroll
    for (int i = 0; i < 16; ++i) { st += ps[i][p16]; st2 += ps2[i][p16]; }
    float m = st * (1.f / 192.f);
    float inv = rsqrtf(st2 * (1.f / 192.f) - m * m + 1e-5f);
    for (int j = 0; j < 12; ++j) {
        int d = sl * 12 + j;
        float val = (yv[d * 17 + p16] - m) * inv * ong[d] + onb[d];
        float zz = z_buf[(b * DI + d) * LL + p];
        float sig = 1.f / (1.f + __expf(-zz));
        t_buf[(b * DI + d) * LL + p] = val * zz * sig;
    }
}

// ---------------- K7a: fused matmul (conv_out | t@W2) + fus_b -> fusedT (B,96,L) --------
__global__ __launch_bounds__(256) void k7a_mm(const float* __restrict__ t_buf,
    const float* __restrict__ conv_out, const float* __restrict__ W2,
    const float* __restrict__ fus_w, const float* __restrict__ fus_b,
    float* __restrict__ fusedT) {
    int t0 = blockIdx.x * 64;
    int og = blockIdx.y;
    int b = blockIdx.z;
    int lane = threadIdx.x & 63;
    int wvu = __builtin_amdgcn_readfirstlane(threadIdx.x >> 6);
    __shared__ float ct[CC * 65];      // [c][p]
    const float* cb = conv_out + (b * LL + t0) * CC;
    for (int e = threadIdx.x; e < 64 * CC; e += 256) {
        int p = e / CC, c = e % CC;
        ct[c * 65 + p] = cb[e];
    }
    __syncthreads();
    int o0 = og * 12 + wvu * 3;
    float acc[3];
    #pragma unroll
    for (int j = 0; j < 3; ++j) acc[j] = fus_b[o0 + j];
    int p = t0 + lane;
    const float* w2 = W2 + o0 * DI;          // uniform -> s_load
    for (int d = 0; d < DI; ++d) {
        float tv = t_buf[(b * DI + d) * LL + p];
        #pragma unroll
        for (int j = 0; j < 3; ++j)
            acc[j] += tv * w2[j * DI + d];
    }
    const float* fw = fus_w + o0 * DI;       // uniform -> s_load (cols 0..95)
    for (int c = 0; c < CC; ++c) {
        float cv = ct[c * 65 + lane];
        #pragma unroll
        for (int j = 0; j < 3; ++j)
            acc[j] += cv * fw[j * DI + c];
    }
    #pragma unroll
    for (int j = 0; j < 3; ++j)
        fusedT[(b * CC + o0 + j) * LL + p] = acc[j];
}

// ---------------- K7b: LN + residual -> out ----------------
__global__ __launch_bounds__(256) void k7b_ln(const float* __restrict__ fusedT,
    const float* __restrict__ flg, const float* __restrict__ flb,
    const float* __restrict__ x, float* __restrict__ out) {
    int t0 = blockIdx.x * 16;
    int b = blockIdx.y;
    int p16 = threadIdx.x & 15, sl = threadIdx.x >> 4;
    __shared__ float ft[CC * 17];      // [o][p16]
    __shared__ float res[16 * 97];
    __shared__ float ps[16][16], ps2[16][16];
    for (int e = threadIdx.x; e < CC * 16; e += 256) {
        int o = e >> 4, p = e & 15;
        ft[o * 17 + p] = fusedT[(b * CC + o) * LL + t0 + p];
    }
    __syncthreads();
    float s = 0.f, s2 = 0.f;
    #pragma unroll
    for (int j = 0; j < 6; ++j) {
        float v = ft[(sl * 6 + j) * 17 + p16];
        s += v; s2 += v * v;
    }
    ps[sl][p16] = s; ps2[sl][p16] = s2;
    __syncthreads();
    float st = 0.f, st2 = 0.f;
    #pragma unroll
    for (int i = 0; i < 16; ++i) { st += ps[i][p16]; st2 += ps2[i][p16]; }
    float m = st * (1.f / 96.f);
    float inv = rsqrtf(st2 * (1.f / 96.f) - m * m + 1e-5f);
    #pragma unroll
    for (int j = 0; j < 6; ++j) {
        int o = sl * 6 + j;
        res[p16 * 97 + o] = (ft[o * 17 + p16] - m) * inv * flg[o] + flb[o];
    }
    __syncthreads();
    const float* xb = x + (b * LL + t0) * CC;
    float* ob = out + (b * LL + t0) * CC;
    for (int e = threadIdx.x; e < 16 * CC; e += 256) {
        int pl = e / CC, o = e % CC;
        ob[e] = xb[e] + res[pl * 97 + o];
    }
}

extern "C" void kernel_launch(void* const* d_in, const int* in_sizes, int n_in,
                              void* d_out, int out_size, void* d_ws, size_t ws_size,
                              hipStream_t stream) {
    const float* x        = (const float*)d_in[0];
    const float* dw_w     = (const float*)d_in[1];
    const float* dw_b     = (const float*)d_in[2];
    const float* bn1_g    = (const float*)d_in[3];
    const float* bn1_b    = (const float*)d_in[4];
    const float* bn1_m    = (const float*)d_in[5];
    const float* bn1_v    = (const float*)d_in[6];
    const float* pw_w     = (const float*)d_in[7];
    const float* pw_b     = (const float*)d_in[8];
    const float* bn2_g    = (const float*)d_in[9];
    const float* bn2_b    = (const float*)d_in[10];
    const float* bn2_m    = (const float*)d_in[11];
    const float* bn2_v    = (const float*)d_in[12];
    const float* ln_g     = (const float*)d_in[13];
    const float* ln_b     = (const float*)d_in[14];
    const float* ipw      = (const float*)d_in[15];
    const float* conv_w   = (const float*)d_in[16];
    const float* conv_b   = (const float*)d_in[17];
    const float* xpw      = (const float*)d_in[18];
    const float* dtw      = (const float*)d_in[19];
    const float* dtb      = (const float*)d_in[20];
    const float* A_logs   = (const float*)d_in[21];
    const float* Ds       = (const float*)d_in[22];
    const float* ong      = (const float*)d_in[23];
    const float* onb      = (const float*)d_in[24];
    const float* opw      = (const float*)d_in[25];
    const float* fus_w    = (const float*)d_in[26];
    const float* fus_b    = (const float*)d_in[27];
    const float* flg      = (const float*)d_in[28];
    const float* flb      = (const float*)d_in[29];

    float* ws = (float*)d_ws;
    float* conv_out = ws + OFF_CONV;
    float* xm_raw   = ws + OFF_XMRAW;
    float* z_buf    = ws + OFF_Z;
    float* v1       = ws + OFF_V1;
    float* v2       = ws + OFF_V2;
    float* dt_s     = ws + OFF_DT;
    float* B_s      = ws + OFF_BS;
    float* C_s      = ws + OFF_CS;
    float* y_scan   = ws + OFF_Y;
    float* y13t     = ws + OFF_Y13;
    float* t_buf    = ws + OFF_T;
    float* W2       = ws + OFF_W2;
    // Aliases (lifetime-disjoint):
    float* cbuf     = y13t;            // k1a/k1b scratch (before scan)
    float* hl_buf   = y13t;            // hlast -> (in-place) hin
    float* Tbuf     = xm_raw;          // chunk dt totals (xm_raw dead after k3); 150528 floats
    float* dtr_g    = xm_raw + 262144; // rank-6 dt rows (150528 floats, disjoint from Tbuf)
    float* negA     = B_s;             // B_s dead after k5a
    float* fusedT   = y13t;            // after k6 consumed y13t
    float* out      = (float*)d_out;

    k0_w2<<<dim3((CC * DI + 63) / 64), dim3(64), 0, stream>>>(fus_w, opw, W2);
    k1a_dw<<<dim3((BZ * LL * CC + 255) / 256), dim3(256), 0, stream>>>(x, dw_w, dw_b,
                                                     bn1_g, bn1_b, bn1_m, bn1_v, cbuf);
    k1b_pw<<<dim3(NT, 2, BZ), dim3(256), 0, stream>>>(cbuf, pw_w, pw_b,
                                                   bn2_g, bn2_b, bn2_m, bn2_v, conv_out);
    k2_inproj<<<dim3(NT, 8, BZ), dim3(256), 0, stream>>>(x, ln_g, ln_b, ipw, xm_raw, z_buf);
    k3_dw<<<dim3(BZ * DI, 2), dim3(256), 0, stream>>>(xm_raw, conv_w, conv_b, v1, v2);
    k4a_xproj<<<dim3(NT, 4, BZ), dim3(256), 0, stream>>>(v1, v2, xpw, dtr_g, B_s, C_s);
    k4b_dt<<<dim3(NT, 4, BZ), dim3(256), 0, stream>>>(dtr_g, dtw, dtb, dt_s);
    k5a_scan<<<dim3(3 * NCH, 4, BZ), dim3(64), 0, stream>>>(dt_s, B_s, C_s, v1, v2, A_logs,
                                                            y_scan, hl_buf, Tbuf);
    k0c_negA<<<dim3(48), dim3(256), 0, stream>>>(A_logs, negA);
    k5c_comb<<<dim3(48, 4, BZ), dim3(64), 0, stream>>>(hl_buf, Tbuf, negA);
    k5d_corr<<<dim3(NCH - 1, 4, BZ), dim3(256), 0, stream>>>(dt_s, C_s, hl_buf, negA, y_scan);
    k5b_tr<<<dim3(BZ * 2 * DI), dim3(256), 0, stream>>>(y_scan, y13t);
    k6_gather<<<dim3(196, BZ), dim3(256), 0, stream>>>(y_scan, y13t, v1, z_buf, Ds, ong, onb, t_buf);
    k7a_mm<<<dim3(NT, 8, BZ), dim3(256), 0, stream>>>(t_buf, conv_out, W2, fus_w, fus_b, fusedT);
    k7b_ln<<<dim3(196, BZ), dim3(256), 0, stream>>>(fusedT, flg, flb, x, out);
}

// Round 11
// 364.231 us; speedup vs baseline: 1.4656x; 1.4656x over previous
//
#include <hip/hip_runtime.h>
#include <math.h>

// Problem constants
#define BZ 2
#define HH 56
#define WW 56
#define LL 3136      // 56*56
#define CC 96        // DIM
#define DI 192       // DINNER
#define NS 16        // DSTATE
#define RR 6         // DTRANK
#define NT 49        // LL/64
#define NCH 98       // scan chunks (32 positions each)
#define CH 32        // chunk length

// Workspace layout (floats)
#define OFF_CONV   0
#define OFF_XMRAW  602112
#define OFF_Z      1806336
#define OFF_V1     3010560
#define OFF_V2     4214784
#define OFF_DT     5419008
#define OFF_BS     10235904
#define OFF_CS     10637312
#define OFF_Y      11038720
#define OFF_Y13    15855616
#define OFF_T      18264064
#define OFF_W2     19468288
// total 19486720 floats = ~78 MB

__device__ __forceinline__ float softplusf(float x) {
    if (x > 20.f) return x;
    return log1pf(__expf(x));
}

// ---------------- K0: W2[o][d] = sum_j fus_w[o][96+j] * out_proj_w[j][d] ----------------
__global__ __launch_bounds__(64) void k0_w2(const float* __restrict__ fus_w,
                                            const float* __restrict__ opw,
                                            float* __restrict__ W2) {
    int i = blockIdx.x * 64 + threadIdx.x;
    if (i >= CC * DI) return;
    int o = i / DI, d = i % DI;
    float acc = 0.f;
    for (int j = 0; j < CC; ++j)
        acc += fus_w[o * DI + CC + j] * opw[j * DI + d];
    W2[i] = acc;
}

// ---------------- K0c: negA[k][d][n] = -exp(A_logs) ----------------
__global__ __launch_bounds__(256) void k0c_negA(const float* __restrict__ A_logs,
                                                float* __restrict__ negA) {
    int i = blockIdx.x * 256 + threadIdx.x;
    if (i < 4 * DI * NS) negA[i] = -__expf(A_logs[i]);
}

// ---------------- K1a: dwconv3 + bn1 + relu (elementwise, fully parallel) ----------------
__global__ __launch_bounds__(256) void k1a_dw(const float* __restrict__ x,
    const float* __restrict__ dw_w, const float* __restrict__ dw_b,
    const float* __restrict__ bn1_g, const float* __restrict__ bn1_b,
    const float* __restrict__ bn1_m, const float* __restrict__ bn1_v,
    float* __restrict__ cbuf) {
    int i = blockIdx.x * 256 + threadIdx.x;
    if (i >= BZ * LL * CC) return;
    int c = i % CC;
    int bl = i / CC;
    int l = bl % LL, b = bl / LL;
    int h = l / WW, w = l % WW;
    float acc = dw_b[c];
    #pragma unroll
    for (int dy = -1; dy <= 1; ++dy) {
        int hh = h + dy; if (hh < 0 || hh >= HH) continue;
        #pragma unroll
        for (int dx = -1; dx <= 1; ++dx) {
            int ww = w + dx; if (ww < 0 || ww >= WW) continue;
            acc += x[((b * HH + hh) * WW + ww) * CC + c] * dw_w[c * 9 + (dy + 1) * 3 + (dx + 1)];
        }
    }
    float inv = rsqrtf(bn1_v[c] + 1e-5f);
    float v = (acc - bn1_m[c]) * inv * bn1_g[c] + bn1_b[c];
    cbuf[i] = fmaxf(v, 0.f);
}

// ---------------- K1b: 1x1 conv (pw) + bn2 -> conv_out (B,L,96) NHWC ----------------
__global__ __launch_bounds__(256) void k1b_pw(const float* __restrict__ cbuf,
    const float* __restrict__ pw_w, const float* __restrict__ pw_b,
    const float* __restrict__ bn2_g, const float* __restrict__ bn2_b,
    const float* __restrict__ bn2_m, const float* __restrict__ bn2_v,
    float* __restrict__ conv_out) {
    int t0 = blockIdx.x * 64;
    int og = blockIdx.y;
    int b = blockIdx.z;
    int lane = threadIdx.x & 63;
    int wvu = __builtin_amdgcn_readfirstlane(threadIdx.x >> 6);
    __shared__ float ct[CC * 65];      // [c][p]
    __shared__ float res[64 * 49];     // [p][48 outs + pad]
    const float* cb = cbuf + (b * LL + t0) * CC;
    for (int e = threadIdx.x; e < 64 * CC; e += 256) {
        int p = e / CC, c = e % CC;
        ct[c * 65 + p] = cb[e];
    }
    __syncthreads();
    int o0 = og * 48 + wvu * 12;
    float acc[12];
    const float* pb = pw_b + o0;
    #pragma unroll
    for (int j = 0; j < 12; ++j) acc[j] = pb[j];
    const float* wb = pw_w + o0 * CC;              // uniform -> s_load
    for (int c = 0; c < CC; ++c) {
        float xv = ct[c * 65 + lane];
        #pragma unroll
        for (int j = 0; j < 12; ++j)
            acc[j] += xv * wb[j * CC + c];
    }
    #pragma unroll
    for (int j = 0; j < 12; ++j) {
        int o = o0 + j;
        float inv = rsqrtf(bn2_v[o] + 1e-5f);
        res[lane * 49 + wvu * 12 + j] = (acc[j] - bn2_m[o]) * inv * bn2_g[o] + bn2_b[o];
    }
    __syncthreads();
    float* ob = conv_out + (b * LL + t0) * CC + og * 48;
    for (int e = threadIdx.x; e < 64 * 48; e += 256) {
        int pl = e / 48, o = e % 48;
        ob[pl * CC + o] = res[pl * 49 + o];
    }
}

// ---------------- K2: LN + in_proj -> xm_raw (B,192,L), z (B,192,L) ----------------
__global__ __launch_bounds__(256) void k2_inproj(const float* __restrict__ x,
    const float* __restrict__ ln_g, const float* __restrict__ ln_b,
    const float* __restrict__ ipw,
    float* __restrict__ xm_raw, float* __restrict__ z_buf) {
    int t0 = blockIdx.x * 64;
    int og = blockIdx.y;       // 0..7, 48 outputs each
    int b = blockIdx.z;
    int lane = threadIdx.x & 63;
    int wv = threadIdx.x >> 6;
    int wvu = __builtin_amdgcn_readfirstlane(wv);
    __shared__ float xt[64 * 97];      // [p][c]
    __shared__ float xn[96 * 65];      // [c][p] normalized
    __shared__ float ps[4][64], ps2[4][64];
    const float* xb = x + (b * LL + t0) * CC;
    for (int e = threadIdx.x; e < 64 * CC; e += 256) {
        int p = e / CC, c = e % CC;
        xt[p * 97 + c] = xb[e];
    }
    __syncthreads();
    float s = 0.f, s2 = 0.f;
    #pragma unroll
    for (int j = 0; j < 24; ++j) {
        float v = xt[lane * 97 + wvu * 24 + j];
        s += v; s2 += v * v;
    }
    ps[wv][lane] = s; ps2[wv][lane] = s2;
    __syncthreads();
    float st = 0.f, st2 = 0.f;
    #pragma unroll
    for (int i = 0; i < 4; ++i) { st += ps[i][lane]; st2 += ps2[i][lane]; }
    float m = st * (1.f / 96.f);
    float inv = rsqrtf(st2 * (1.f / 96.f) - m * m + 1e-5f);
    #pragma unroll
    for (int j = 0; j < 24; ++j) {
        int c = wvu * 24 + j;
        xn[c * 65 + lane] = (xt[lane * 97 + c] - m) * inv * ln_g[c] + ln_b[c];
    }
    __syncthreads();
    float acc[12];
    #pragma unroll
    for (int j = 0; j < 12; ++j) acc[j] = 0.f;
    int o0 = og * 48 + wvu * 12;
    const float* wbase = ipw + o0 * CC;       // uniform -> s_load
    for (int c = 0; c < CC; ++c) {
        float xv = xn[c * 65 + lane];
        #pragma unroll
        for (int j = 0; j < 12; ++j)
            acc[j] += xv * wbase[j * CC + c];
    }
    int p = t0 + lane;
    #pragma unroll
    for (int j = 0; j < 12; ++j) {
        int out = o0 + j;
        if (out < DI) xm_raw[(b * DI + out) * LL + p] = acc[j];
        else          z_buf[(b * DI + (out - DI)) * LL + p] = acc[j];
    }
}

// ---------------- K3: dwconv3 + SiLU -> v1 (row-major), v2 (col-major) ----------------
__global__ __launch_bounds__(256) void k3_dw(const float* __restrict__ xm_raw,
    const float* __restrict__ conv_w, const float* __restrict__ conv_b,
    float* __restrict__ v1, float* __restrict__ v2) {
    int bd = blockIdx.x;
    int half = blockIdx.y;
    int d = bd % DI;
    int h0 = half * 28;
    __shared__ float tile[28 * 57];
    const float* src = xm_raw + bd * LL;
    float wloc[9];
    #pragma unroll
    for (int i = 0; i < 9; ++i) wloc[i] = conv_w[d * 9 + i];
    float bias = conv_b[d];
    for (int e = threadIdx.x; e < 28 * WW; e += 256) {
        int hl = e / WW, w = e % WW;
        int h = h0 + hl;
        float acc = bias;
        #pragma unroll
        for (int dy = -1; dy <= 1; ++dy) {
            int hh = h + dy; if (hh < 0 || hh >= HH) continue;
            #pragma unroll
            for (int dx = -1; dx <= 1; ++dx) {
                int ww = w + dx; if (ww < 0 || ww >= WW) continue;
                acc += src[hh * WW + ww] * wloc[(dy + 1) * 3 + (dx + 1)];
            }
        }
        float sig = 1.f / (1.f + __expf(-acc));
        float v = acc * sig;
        v1[bd * LL + h * WW + w] = v;
        tile[hl * 57 + w] = v;
    }
    __syncthreads();
    for (int e = threadIdx.x; e < 28 * WW; e += 256) {
        int w = e / 28, hl = e % 28;
        v2[bd * LL + w * HH + h0 + hl] = tile[hl * 57 + w];
    }
}

// ---------------- K4a: x_proj — 4-wave blocks, no LDS, 10 rows/wave ----------------
__global__ __launch_bounds__(256) void k4a_xproj(const float* __restrict__ v1,
    const float* __restrict__ v2, const float* __restrict__ xpw,
    float* __restrict__ dtr_g, float* __restrict__ B_s, float* __restrict__ C_s) {
    int tile = blockIdx.x;
    int k = blockIdx.y, b = blockIdx.z;
    int lane = threadIdx.x & 63;
    int wvu = __builtin_amdgcn_readfirstlane(threadIdx.x >> 6);
    int t0 = tile * 64;
    int r0 = wvu * 10; if (r0 > 28) r0 = 28;
    const float* src = ((k & 1) == 0 ? v1 : v2) + b * DI * LL + t0;
    float acc[10];
    #pragma unroll
    for (int i = 0; i < 10; ++i) acc[i] = 0.f;
    const float* wbase = xpw + (k * 38 + r0) * DI;   // uniform -> s_load
    for (int d = 0; d < DI; ++d) {
        float xv = src[d * LL + lane];
        #pragma unroll
        for (int i = 0; i < 10; ++i)
            acc[i] += xv * wbase[i * DI + d];
    }
    int bk = b * 4 + k;
    int p = t0 + lane;
    #pragma unroll
    for (int i = 0; i < 10; ++i) {
        int c = r0 + i;
        if (c < RR) {
            dtr_g[(bk * RR + c) * LL + p] = acc[i];
        } else if (c < RR + NS) {
            B_s[(bk * NS + (c - RR)) * LL + p] = acc[i];
        } else {
            C_s[(bk * NS + (c - RR - NS)) * LL + p] = acc[i];
        }
    }
}

// ---------------- K4b: dt_proj + softplus (streaming write) ----------------
__global__ __launch_bounds__(256) void k4b_dt(const float* __restrict__ dtr_g,
    const float* __restrict__ dtw, const float* __restrict__ dtb,
    float* __restrict__ dt_s) {
    int t0 = blockIdx.x * 64;
    int k = blockIdx.y, b = blockIdx.z;
    int lane = threadIdx.x & 63;
    int wvu = __builtin_amdgcn_readfirstlane(threadIdx.x >> 6);
    int bk = b * 4 + k;
    int p = t0 + lane;
    float r[RR];
    #pragma unroll
    for (int i = 0; i < RR; ++i) r[i] = dtr_g[(bk * RR + i) * LL + p];
    for (int i = 0; i < 48; ++i) {
        int d = wvu * 48 + i;
        float a = dtb[k * DI + d];
        const float* wr = dtw + (k * DI + d) * RR;   // uniform -> s_load
        #pragma unroll
        for (int q = 0; q < RR; ++q)
            a += r[q] * wr[q];
        dt_s[(bk * DI + d) * LL + p] = softplusf(a);
    }
}

// ---------------- K5a: scan phase 1 — 2 waves split the 16 n-states ----------------
// Block 128 = 2 waves, one chunk. LDS dtl/ul staged in SCAN ORDER (si reversal for
// backward) so the step loop is forward-only with static indices; per-wave y
// partials in statically-indexed registers, combined via dtl/ul after the loop.
__global__ __launch_bounds__(128) void k5a_scan(const float* __restrict__ dt_s,
    const float* __restrict__ B_s, const float* __restrict__ C_s,
    const float* __restrict__ v1, const float* __restrict__ v2,
    const float* __restrict__ A_logs, float* __restrict__ y_scan,
    float* __restrict__ hl_buf, float* __restrict__ Tbuf) {
    int bx = blockIdx.x;
    int dg = bx % 3, c = bx / 3;
    int k = blockIdx.y, b = blockIdx.z;
    int bk = b * 4 + k;
    int tid = threadIdx.x;
    int lane = tid & 63;
    int wvu = __builtin_amdgcn_readfirstlane(tid >> 6);   // n-half: 0 or 1
    int d0 = dg * 64, d = d0 + lane;
    bool fwd = (k < 2);
    int s0 = fwd ? c * CH : (LL - (c + 1) * CH);
    __shared__ float dtl[64 * 33];     // [d-row][scan-pos]
    __shared__ float ul[64 * 33];
    __shared__ float bc[CH * 36];      // [scan-pos][36]: B 0..15, C 16..31, pad
    float Ae[8];
    const float* ap = A_logs + (k * DI + d) * NS + wvu * 8;
    #pragma unroll
    for (int n = 0; n < 8; ++n) Ae[n] = -__expf(ap[n]) * 1.442695040888963f;
    const float* dtp = dt_s + (bk * DI + d0) * LL + s0;
    const float* up  = ((k & 1) == 0 ? v1 : v2) + (b * DI + d0) * LL + s0;
    int pr = tid >> 5, pc = tid & 31;                 // pr 0..3
    int si = fwd ? pc : (31 - pc);                    // scan-order slot
    #pragma unroll
    for (int i = 0; i < 16; ++i) {
        int row = i * 4 + pr;
        dtl[row * 33 + si] = dtp[row * LL + pc];
        ul[row * 33 + si]  = up[row * LL + pc];
    }
    #pragma unroll
    for (int i = 0; i < 4; ++i) {
        int nn = i * 4 + pr;
        bc[si * 36 + nn]      = B_s[(bk * NS + nn) * LL + s0 + pc];
        bc[si * 36 + 16 + nn] = C_s[(bk * NS + nn) * LL + s0 + pc];
    }
    __syncthreads();
    float h[8];
    #pragma unroll
    for (int n = 0; n < 8; ++n) h[n] = 0.f;
    float cum = 0.f;
    float yv_[CH];
    #pragma unroll
    for (int j = 0; j < CH; ++j) {                    // forward-only, static j
        float dtv = dtl[lane * 33 + j];
        float uv  = ul[lane * 33 + j];
        float du = dtv * uv;
        cum += dtv;
        const float* rb = &bc[j * 36 + wvu * 8];
        const float* rc = &bc[j * 36 + 16 + wvu * 8];
        float4 b0 = *(const float4*)rb, b1 = *(const float4*)(rb + 4);
        float4 c0 = *(const float4*)rc, c1 = *(const float4*)(rc + 4);
        float bv[8] = {b0.x, b0.y, b0.z, b0.w, b1.x, b1.y, b1.z, b1.w};
        float cv[8] = {c0.x, c0.y, c0.z, c0.w, c1.x, c1.y, c1.z, c1.w};
        float y = 0.f;
        #pragma unroll
        for (int n = 0; n < 8; ++n) {
            h[n] = exp2f(dtv * Ae[n]) * h[n] + du * bv[n];
            y += h[n] * cv[n];
        }
        yv_[j] = y;                                   // static index -> register
    }
    __syncthreads();                                  // both waves done with dt/u
    if (wvu == 0) {
        #pragma unroll
        for (int j = 0; j < CH; ++j) dtl[lane * 33 + j] = yv_[j];
    } else {
        #pragma unroll
        for (int j = 0; j < CH; ++j) ul[lane * 33 + j] = yv_[j];
    }
    __syncthreads();
    // flush y: global position pc maps to scan slot si
    float* yp = y_scan + (bk * DI + d0) * LL + s0;
    #pragma unroll
    for (int i = 0; i < 16; ++i) {
        int row = i * 4 + pr;
        yp[row * LL + pc] = dtl[row * 33 + si] + ul[row * 33 + si];
    }
    // hlast: each wave owns its 8 n-states
    float4* hp4 = (float4*)(hl_buf + (bk * NCH + c) * (DI * NS) + d * NS + wvu * 8);
    hp4[0] = make_float4(h[0], h[1], h[2], h[3]);
    hp4[1] = make_float4(h[4], h[5], h[6], h[7]);
    if (wvu == 0) Tbuf[(bk * NCH + c) * DI + d] = cum;
}

// ---------------- K5c: scan phase 2 — serial chunk combine, in place, prefetched --------
__global__ __launch_bounds__(64) void k5c_comb(float* __restrict__ hl_buf,
    const float* __restrict__ Tbuf, const float* __restrict__ negA) {
    int dg = blockIdx.x, k = blockIdx.y, b = blockIdx.z;
    int lane = threadIdx.x, dl = lane >> 4, n = lane & 15;
    int d = dg * 4 + dl;
    int bk = b * 4 + k;
    float Av = negA[(k * DI + d) * NS + n];
    float H = 0.f;
    float* slot0 = hl_buf + (bk * NCH + 0) * (DI * NS) + dg * 64 + lane;
    float hl_next = *slot0;
    float T_next = Tbuf[(bk * NCH + 0) * DI + d];
    for (int c = 0; c < NCH; ++c) {
        float hl = hl_next, T = T_next;
        if (c + 1 < NCH) {
            hl_next = hl_buf[(bk * NCH + c + 1) * (DI * NS) + dg * 64 + lane];
            T_next  = Tbuf[(bk * NCH + c + 1) * DI + d];
        }
        hl_buf[(bk * NCH + c) * (DI * NS) + dg * 64 + lane] = H;
        H = hl + __expf(Av * T) * H;
    }
}

// ---------------- K5d: scan phase 3 — parallel correction (prefix via shfl) ----------
__global__ __launch_bounds__(256) void k5d_corr(const float* __restrict__ dt_s,
    const float* __restrict__ C_s, const float* __restrict__ hin,
    const float* __restrict__ negA, float* __restrict__ y_scan) {
    int t = blockIdx.x;
    int k = blockIdx.y, b = blockIdx.z;
    bool fwd = (k < 2);
    int c  = fwd ? (t + 1) : (NCH - 1 - t);
    int s0 = fwd ? (t + 1) * CH : t * CH;
    int p32 = threadIdx.x & 31, sl = threadIdx.x >> 5;
    int bk = b * 4 + k;
    __shared__ float c_l[16 * 33];
    for (int e = threadIdx.x; e < 16 * CH; e += 256) {
        int n = e >> 5, s = e & 31;
        c_l[n * 33 + s] = C_s[(bk * NS + n) * LL + s0 + s];
    }
    __syncthreads();
    for (int j = 0; j < 24; ++j) {
        int d = sl * 24 + j;
        float dtv = dt_s[(bk * DI + d) * LL + s0 + p32];
        float cum = dtv;
        if (fwd) {
            #pragma unroll
            for (int off = 1; off < 32; off <<= 1) {
                float o = __shfl_up(cum, off, 32);
                if (p32 >= off) cum += o;
            }
        } else {
            #pragma unroll
            for (int off = 1; off < 32; off <<= 1) {
                float o = __shfl_down(cum, off, 32);
                if (p32 < 32 - off) cum += o;
            }
        }
        const float* hp = hin + (bk * NCH + c) * (DI * NS) + d * 16;
        const float* ap = negA + (k * DI + d) * NS;
        float acc = 0.f;
        #pragma unroll
        for (int n = 0; n < 16; ++n) {
            acc += c_l[n * 33 + p32] * __expf(ap[n] * cum) * hp[n];
        }
        y_scan[(bk * DI + d) * LL + s0 + p32] += acc;
    }
}

// ---------------- K5b: transpose y for k=1,3 ----------------
__global__ __launch_bounds__(256) void k5b_tr(const float* __restrict__ y_scan,
                                              float* __restrict__ y13t) {
    int idx = blockIdx.x;
    int d = idx % DI;
    int bk = idx / DI;
    int kk = bk % 2, b = bk / 2;
    int k = (kk == 0) ? 1 : 3;
    __shared__ float tile[HH * 57];
    const float* src = y_scan + ((b * 4 + k) * DI + d) * LL;
    for (int e = threadIdx.x; e < LL; e += 256) {
        int w = e / HH, h = e % HH;
        tile[h * 57 + w] = src[e];
    }
    __syncthreads();
    float* dst = y13t + idx * LL;
    for (int e = threadIdx.x; e < LL; e += 256) {
        int h = e / WW, w = e % WW;
        dst[e] = tile[h * 57 + w];
    }
}

// ---------------- K6: gather 4 dirs + D*u + out_norm + silu(z) gate -> t ----------------
__global__ __launch_bounds__(256) void k6_gather(const float* __restrict__ y_scan,
    const float* __restrict__ y13t, const float* __restrict__ v1,
    const float* __restrict__ z_buf, const float* __restrict__ Ds,
    const float* __restrict__ ong, const float* __restrict__ onb,
    float* __restrict__ t_buf) {
    int t0 = blockIdx.x * 16;
    int b = blockIdx.y;
    int p16 = threadIdx.x & 15, sl = threadIdx.x >> 4;
    int p = t0 + p16;
    __shared__ float yv[DI * 17];
    __shared__ float ps[16][16], ps2[16][16];
    float s = 0.f, s2 = 0.f;
    for (int j = 0; j < 12; ++j) {
        int d = sl * 12 + j;
        float dsum = Ds[d] + Ds[DI + d] + Ds[2 * DI + d] + Ds[3 * DI + d];
        float val = y_scan[((b * 4 + 0) * DI + d) * LL + p]
                  + y_scan[((b * 4 + 2) * DI + d) * LL + p]
                  + y13t[((b * 2 + 0) * DI + d) * LL + p]
                  + y13t[((b * 2 + 1) * DI + d) * LL + p]
                  + v1[(b * DI + d) * LL + p] * dsum;
        yv[d * 17 + p16] = val;
        s += val; s2 += val * val;
    }
    ps[sl][p16] = s; ps2[sl][p16] = s2;
    __syncthreads();
    float st = 0.f, st2 = 0.f;
    #pragma unroll
    for (int i = 0; i < 16; ++i) { st += ps[i][p16]; st2 += ps2[i][p16]; }
    float m = st * (1.f / 192.f);
    float inv = rsqrtf(st2 * (1.f / 192.f) - m * m + 1e-5f);
    for (int j = 0; j < 12; ++j) {
        int d = sl * 12 + j;
        float val = (yv[d * 17 + p16] - m) * inv * ong[d] + onb[d];
        float zz = z_buf[(b * DI + d) * LL + p];
        float sig = 1.f / (1.f + __expf(-zz));
        t_buf[(b * DI + d) * LL + p] = val * zz * sig;
    }
}

// ---------------- K7a: fused matmul (conv_out | t@W2) + fus_b -> fusedT (B,96,L) --------
__global__ __launch_bounds__(256) void k7a_mm(const float* __restrict__ t_buf,
    const float* __restrict__ conv_out, const float* __restrict__ W2,
    const float* __restrict__ fus_w, const float* __restrict__ fus_b,
    float* __restrict__ fusedT) {
    int t0 = blockIdx.x * 64;
    int og = blockIdx.y;
    int b = blockIdx.z;
    int lane = threadIdx.x & 63;
    int wvu = __builtin_amdgcn_readfirstlane(threadIdx.x >> 6);
    __shared__ float ct[CC * 65];      // [c][p]
    const float* cb = conv_out + (b * LL + t0) * CC;
    for (int e = threadIdx.x; e < 64 * CC; e += 256) {
        int p = e / CC, c = e % CC;
        ct[c * 65 + p] = cb[e];
    }
    __syncthreads();
    int o0 = og * 12 + wvu * 3;
    float acc[3];
    #pragma unroll
    for (int j = 0; j < 3; ++j) acc[j] = fus_b[o0 + j];
    int p = t0 + lane;
    const float* w2 = W2 + o0 * DI;          // uniform -> s_load
    for (int d = 0; d < DI; ++d) {
        float tv = t_buf[(b * DI + d) * LL + p];
        #pragma unroll
        for (int j = 0; j < 3; ++j)
            acc[j] += tv * w2[j * DI + d];
    }
    const float* fw = fus_w + o0 * DI;       // uniform -> s_load (cols 0..95)
    for (int c = 0; c < CC; ++c) {
        float cv = ct[c * 65 + lane];
        #pragma unroll
        for (int j = 0; j < 3; ++j)
            acc[j] += cv * fw[j * DI + c];
    }
    #pragma unroll
    for (int j = 0; j < 3; ++j)
        fusedT[(b * CC + o0 + j) * LL + p] = acc[j];
}

// ---------------- K7b: LN + residual -> out ----------------
__global__ __launch_bounds__(256) void k7b_ln(const float* __restrict__ fusedT,
    const float* __restrict__ flg, const float* __restrict__ flb,
    const float* __restrict__ x, float* __restrict__ out) {
    int t0 = blockIdx.x * 16;
    int b = blockIdx.y;
    int p16 = threadIdx.x & 15, sl = threadIdx.x >> 4;
    __shared__ float ft[CC * 17];      // [o][p16]
    __shared__ float res[16 * 97];
    __shared__ float ps[16][16], ps2[16][16];
    for (int e = threadIdx.x; e < CC * 16; e += 256) {
        int o = e >> 4, p = e & 15;
        ft[o * 17 + p] = fusedT[(b * CC + o) * LL + t0 + p];
    }
    __syncthreads();
    float s = 0.f, s2 = 0.f;
    #pragma unroll
    for (int j = 0; j < 6; ++j) {
        float v = ft[(sl * 6 + j) * 17 + p16];
        s += v; s2 += v * v;
    }
    ps[sl][p16] = s; ps2[sl][p16] = s2;
    __syncthreads();
    float st = 0.f, st2 = 0.f;
    #pragma unroll
    for (int i = 0; i < 16; ++i) { st += ps[i][p16]; st2 += ps2[i][p16]; }
    float m = st * (1.f / 96.f);
    float inv = rsqrtf(st2 * (1.f / 96.f) - m * m + 1e-5f);
    #pragma unroll
    for (int j = 0; j < 6; ++j) {
        int o = sl * 6 + j;
        res[p16 * 97 + o] = (ft[o * 17 + p16] - m) * inv * flg[o] + flb[o];
    }
    __syncthreads();
    const float* xb = x + (b * LL + t0) * CC;
    float* ob = out + (b * LL + t0) * CC;
    for (int e = threadIdx.x; e < 16 * CC; e += 256) {
        int pl = e / CC, o = e % CC;
        ob[e] = xb[e] + res[pl * 97 + o];
    }
}

extern "C" void kernel_launch(void* const* d_in, const int* in_sizes, int n_in,
                              void* d_out, int out_size, void* d_ws, size_t ws_size,
                              hipStream_t stream) {
    const float* x        = (const float*)d_in[0];
    const float* dw_w     = (const float*)d_in[1];
    const float* dw_b     = (const float*)d_in[2];
    const float* bn1_g    = (const float*)d_in[3];
    const float* bn1_b    = (const float*)d_in[4];
    const float* bn1_m    = (const float*)d_in[5];
    const float* bn1_v    = (const float*)d_in[6];
    const float* pw_w     = (const float*)d_in[7];
    const float* pw_b     = (const float*)d_in[8];
    const float* bn2_g    = (const float*)d_in[9];
    const float* bn2_b    = (const float*)d_in[10];
    const float* bn2_m    = (const float*)d_in[11];
    const float* bn2_v    = (const float*)d_in[12];
    const float* ln_g     = (const float*)d_in[13];
    const float* ln_b     = (const float*)d_in[14];
    const float* ipw      = (const float*)d_in[15];
    const float* conv_w   = (const float*)d_in[16];
    const float* conv_b   = (const float*)d_in[17];
    const float* xpw      = (const float*)d_in[18];
    const float* dtw      = (const float*)d_in[19];
    const float* dtb      = (const float*)d_in[20];
    const float* A_logs   = (const float*)d_in[21];
    const float* Ds       = (const float*)d_in[22];
    const float* ong      = (const float*)d_in[23];
    const float* onb      = (const float*)d_in[24];
    const float* opw      = (const float*)d_in[25];
    const float* fus_w    = (const float*)d_in[26];
    const float* fus_b    = (const float*)d_in[27];
    const float* flg      = (const float*)d_in[28];
    const float* flb      = (const float*)d_in[29];

    float* ws = (float*)d_ws;
    float* conv_out = ws + OFF_CONV;
    float* xm_raw   = ws + OFF_XMRAW;
    float* z_buf    = ws + OFF_Z;
    float* v1       = ws + OFF_V1;
    float* v2       = ws + OFF_V2;
    float* dt_s     = ws + OFF_DT;
    float* B_s      = ws + OFF_BS;
    float* C_s      = ws + OFF_CS;
    float* y_scan   = ws + OFF_Y;
    float* y13t     = ws + OFF_Y13;
    float* t_buf    = ws + OFF_T;
    float* W2       = ws + OFF_W2;
    // Aliases (lifetime-disjoint):
    float* cbuf     = y13t;            // k1a/k1b scratch (before scan)
    float* hl_buf   = y13t;            // hlast -> (in-place) hin; exact fit
    float* Tbuf     = xm_raw;          // chunk dt totals (xm_raw dead after k3)
    float* dtr_g    = xm_raw + 262144; // rank-6 dt rows (disjoint from Tbuf)
    float* negA     = B_s;             // B_s dead after k5a
    float* fusedT   = y13t;            // after k6 consumed y13t
    float* out      = (float*)d_out;

    k0_w2<<<dim3((CC * DI + 63) / 64), dim3(64), 0, stream>>>(fus_w, opw, W2);
    k1a_dw<<<dim3((BZ * LL * CC + 255) / 256), dim3(256), 0, stream>>>(x, dw_w, dw_b,
                                                     bn1_g, bn1_b, bn1_m, bn1_v, cbuf);
    k1b_pw<<<dim3(NT, 2, BZ), dim3(256), 0, stream>>>(cbuf, pw_w, pw_b,
                                                   bn2_g, bn2_b, bn2_m, bn2_v, conv_out);
    k2_inproj<<<dim3(NT, 8, BZ), dim3(256), 0, stream>>>(x, ln_g, ln_b, ipw, xm_raw, z_buf);
    k3_dw<<<dim3(BZ * DI, 2), dim3(256), 0, stream>>>(xm_raw, conv_w, conv_b, v1, v2);
    k4a_xproj<<<dim3(NT, 4, BZ), dim3(256), 0, stream>>>(v1, v2, xpw, dtr_g, B_s, C_s);
    k4b_dt<<<dim3(NT, 4, BZ), dim3(256), 0, stream>>>(dtr_g, dtw, dtb, dt_s);
    k5a_scan<<<dim3(3 * NCH, 4, BZ), dim3(128), 0, stream>>>(dt_s, B_s, C_s, v1, v2, A_logs,
                                                             y_scan, hl_buf, Tbuf);
    k0c_negA<<<dim3(48), dim3(256), 0, stream>>>(A_logs, negA);
    k5c_comb<<<dim3(48, 4, BZ), dim3(64), 0, stream>>>(hl_buf, Tbuf, negA);
    k5d_corr<<<dim3(NCH - 1, 4, BZ), dim3(256), 0, stream>>>(dt_s, C_s, hl_buf, negA, y_scan);
    k5b_tr<<<dim3(BZ * 2 * DI), dim3(256), 0, stream>>>(y_scan, y13t);
    k6_gather<<<dim3(196, BZ), dim3(256), 0, stream>>>(y_scan, y13t, v1, z_buf, Ds, ong, onb, t_buf);
    k7a_mm<<<dim3(NT, 8, BZ), dim3(256), 0, stream>>>(t_buf, conv_out, W2, fus_w, fus_b, fusedT);
    k7b_ln<<<dim3(196, BZ), dim3(256), 0, stream>>>(fusedT, flg, flb, x, out);
}